// Round 1
// baseline (167.807 us; speedup 1.0000x reference)
//
#include <hip/hip_runtime.h>
#include <hip/hip_bf16.h>

#define TM 8            // template points per thread (register-tiled)
#define BLK 256         // threads per block
#define TPB (BLK * TM)  // 2048 templates per template-chunk
#define SCHUNKS 128     // scan chunks -> grid = 128 x tChunks blocks
#define THRESH 0.1f

// Pack scan points as {-2x, -2y, -2z, |s|^2} and zero the output scalar.
__global__ void pdl_prep(const float* __restrict__ scan, float4* __restrict__ sp,
                         int N, float* __restrict__ out) {
    int i = blockIdx.x * blockDim.x + threadIdx.x;
    if (i == 0) out[0] = 0.0f;
    if (i < N) {
        float x = scan[3 * i + 0];
        float y = scan[3 * i + 1];
        float z = scan[3 * i + 2];
        sp[i] = make_float4(-2.0f * x, -2.0f * y, -2.0f * z, x * x + y * y + z * z);
    }
}

// Each block: one (scan-chunk, template-chunk) tile. Thread register-tiles TM
// templates; scan point is wave-uniform -> scalar loads, 5 VALU ops per pair.
__global__ __launch_bounds__(BLK) void pdl_main(const float* __restrict__ tmpl,
                                                const float4* __restrict__ sp,
                                                float* __restrict__ pmin,
                                                int M, int N, int Mpad, int SC) {
    const int tid = threadIdx.x;
    const int m0 = blockIdx.y * TPB + tid;

    float tx[TM], ty[TM], tz[TM], t2[TM], mn[TM];
#pragma unroll
    for (int k = 0; k < TM; ++k) {
        int m = m0 + k * BLK;
        if (m < M) {
            float x = tmpl[3 * m + 0];
            float y = tmpl[3 * m + 1];
            float z = tmpl[3 * m + 2];
            tx[k] = x; ty[k] = y; tz[k] = z;
            t2[k] = x * x + y * y + z * z;
        } else {
            tx[k] = 0.0f; ty[k] = 0.0f; tz[k] = 0.0f;
            t2[k] = 3e30f;  // padded templates -> huge distance, masked in reduce
        }
        mn[k] = 3e30f;
    }

    const int j0 = blockIdx.x * SC;
    const int j1 = min(j0 + SC, N);
    for (int j = j0; j < j1; ++j) {
        const float4 s = sp[j];  // uniform index -> s_load_dwordx4 (SGPRs)
#pragma unroll
        for (int k = 0; k < TM; ++k) {
            // d2 = (|s|^2 + |t|^2) - 2 s.t  via 1 add + 3 fma
            float d = fmaf(s.x, tx[k],
                      fmaf(s.y, ty[k],
                      fmaf(s.z, tz[k], t2[k] + s.w)));
            mn[k] = fminf(mn[k], d);
        }
    }

#pragma unroll
    for (int k = 0; k < TM; ++k) {
        int m = m0 + k * BLK;
        if (m < M) pmin[(size_t)blockIdx.x * Mpad + m] = mn[k];  // coalesced
    }
}

// min over scan-chunks per template, threshold, block-reduce, atomicAdd.
__global__ __launch_bounds__(BLK) void pdl_reduce(const float* __restrict__ pmin,
                                                  float* __restrict__ out,
                                                  int M, int Mpad, int chunks) {
    const int m = blockIdx.x * BLK + threadIdx.x;
    float v = 3e30f;
    if (m < M) {
        for (int c = 0; c < chunks; ++c)
            v = fminf(v, pmin[(size_t)c * Mpad + m]);  // coalesced across threads
    }
    float s = (m < M && v < THRESH) ? v : 0.0f;

#pragma unroll
    for (int off = 32; off > 0; off >>= 1) s += __shfl_down(s, off, 64);

    __shared__ float ls[BLK / 64];
    const int lane = threadIdx.x & 63;
    const int w = threadIdx.x >> 6;
    if (lane == 0) ls[w] = s;
    __syncthreads();
    if (threadIdx.x == 0) {
        float t = 0.0f;
#pragma unroll
        for (int i = 0; i < BLK / 64; ++i) t += ls[i];
        atomicAdd(out, t);
    }
}

extern "C" void kernel_launch(void* const* d_in, const int* in_sizes, int n_in,
                              void* d_out, int out_size, void* d_ws, size_t ws_size,
                              hipStream_t stream) {
    const float* scan = (const float*)d_in[0];   // [N,3] fp32
    const float* tmpl = (const float*)d_in[1];   // [M,3] fp32
    float* out = (float*)d_out;                  // scalar fp32

    const int N = in_sizes[0] / 3;               // 50000
    const int M = in_sizes[1] / 3;               // 6890

    const int SC = (N + SCHUNKS - 1) / SCHUNKS;  // scan points per chunk (391)
    const int tChunks = (M + TPB - 1) / TPB;     // 4
    const int Mpad = tChunks * TPB;              // 8192

    // ws layout: [0, N*16) packed scan float4 ; then partial-min [SCHUNKS][Mpad]
    float4* sp = (float4*)d_ws;
    float* pmin = (float*)((char*)d_ws + (size_t)N * sizeof(float4));

    pdl_prep<<<(N + BLK - 1) / BLK, BLK, 0, stream>>>(scan, sp, N, out);

    dim3 grid(SCHUNKS, tChunks);
    pdl_main<<<grid, BLK, 0, stream>>>(tmpl, sp, pmin, M, N, Mpad, SC);

    pdl_reduce<<<Mpad / BLK, BLK, 0, stream>>>(pmin, out, M, Mpad, SCHUNKS);
}

// Round 2
// 125.322 us; speedup vs baseline: 1.3390x; 1.3390x over previous
//
#include <hip/hip_runtime.h>
#include <hip/hip_bf16.h>

#define TM 9            // template points per thread (register-tiled)
#define BLK 256         // threads per block
#define TPB (BLK * TM)  // 2304 templates per template-chunk -> 3 chunks = 6912
#define SC 295          // scan points per chunk (ceil(50000/170) -> 170 chunks)
#define SCPAD 304       // padded to multiple of 8 for unroll(2) x batch(4)
#define THRESH 0.1f

// Fused: per-block scan-chunk packing into LDS + register-tiled min-distance.
// Each block: one (scan-chunk, template-chunk) tile. Template tile lives in
// registers; scan points broadcast from LDS (ds_read_b128, conflict-free).
// Inner math: e = |s|^2 - 2 s.t (3 FMA), min-tree over 4 j's, |t|^2 added once
// at the store -> ~3.75 VALU ops per pair.
__global__ __launch_bounds__(BLK) void pdl_main(const float* __restrict__ scan,
                                                const float* __restrict__ tmpl,
                                                float* __restrict__ pmin,
                                                float* __restrict__ out,
                                                int M, int N, int Mpad) {
    __shared__ float4 sp[SCPAD];
    const int tid = threadIdx.x;

    // Zero the output scalar (reduce kernel atomicAdds after this kernel ends;
    // stream ordering makes this visible).
    if (blockIdx.x == 0 && blockIdx.y == 0 && tid == 0) out[0] = 0.0f;

    // Stage + pack this block's scan chunk: {-2x, -2y, -2z, |s|^2}.
    const int j0 = blockIdx.x * SC;
    for (int p = tid; p < SCPAD; p += BLK) {
        const int j = j0 + p;
        float4 q = make_float4(0.0f, 0.0f, 0.0f, 3e30f);  // sentinel: huge dist
        if (p < SC && j < N) {
            const float x = scan[3 * j + 0];
            const float y = scan[3 * j + 1];
            const float z = scan[3 * j + 2];
            q = make_float4(-2.0f * x, -2.0f * y, -2.0f * z, x * x + y * y + z * z);
        }
        sp[p] = q;
    }

    // Register-resident template tile.
    const int m0 = blockIdx.y * TPB + tid;
    float tx[TM], ty[TM], tz[TM], t2[TM], mn[TM];
#pragma unroll
    for (int k = 0; k < TM; ++k) {
        int m = m0 + k * BLK;
        if (m >= M) m = M - 1;  // clamped duplicate; masked out in reduce
        const float x = tmpl[3 * m + 0];
        const float y = tmpl[3 * m + 1];
        const float z = tmpl[3 * m + 2];
        tx[k] = x; ty[k] = y; tz[k] = z;
        t2[k] = x * x + y * y + z * z;
        mn[k] = 3e30f;
    }

    __syncthreads();

#pragma unroll 2
    for (int jj = 0; jj < SCPAD; jj += 4) {
        const float4 s0 = sp[jj + 0];
        const float4 s1 = sp[jj + 1];
        const float4 s2 = sp[jj + 2];
        const float4 s3 = sp[jj + 3];
#pragma unroll
        for (int k = 0; k < TM; ++k) {
            const float e0 = fmaf(s0.x, tx[k], fmaf(s0.y, ty[k], fmaf(s0.z, tz[k], s0.w)));
            const float e1 = fmaf(s1.x, tx[k], fmaf(s1.y, ty[k], fmaf(s1.z, tz[k], s1.w)));
            const float e2 = fmaf(s2.x, tx[k], fmaf(s2.y, ty[k], fmaf(s2.z, tz[k], s2.w)));
            const float e3 = fmaf(s3.x, tx[k], fmaf(s3.y, ty[k], fmaf(s3.z, tz[k], s3.w)));
            mn[k] = fminf(mn[k], fminf(fminf(e0, e1), fminf(e2, e3)));  // -> v_min3
        }
    }

#pragma unroll
    for (int k = 0; k < TM; ++k) {
        const int m = m0 + k * BLK;
        if (m < M) pmin[(size_t)blockIdx.x * Mpad + m] = mn[k] + t2[k];  // coalesced
    }
}

// min over scan-chunks per template, threshold, block-reduce, atomicAdd.
__global__ __launch_bounds__(BLK) void pdl_reduce(const float* __restrict__ pmin,
                                                  float* __restrict__ out,
                                                  int M, int Mpad, int chunks) {
    const int m = blockIdx.x * BLK + threadIdx.x;
    float v = 3e30f;
    if (m < M) {
        for (int c = 0; c < chunks; ++c)
            v = fminf(v, pmin[(size_t)c * Mpad + m]);  // coalesced across threads
    }
    float s = (m < M && v < THRESH) ? v : 0.0f;

#pragma unroll
    for (int off = 32; off > 0; off >>= 1) s += __shfl_down(s, off, 64);

    __shared__ float ls[BLK / 64];
    const int lane = threadIdx.x & 63;
    const int w = threadIdx.x >> 6;
    if (lane == 0) ls[w] = s;
    __syncthreads();
    if (threadIdx.x == 0) {
        float t = 0.0f;
#pragma unroll
        for (int i = 0; i < BLK / 64; ++i) t += ls[i];
        atomicAdd(out, t);
    }
}

extern "C" void kernel_launch(void* const* d_in, const int* in_sizes, int n_in,
                              void* d_out, int out_size, void* d_ws, size_t ws_size,
                              hipStream_t stream) {
    const float* scan = (const float*)d_in[0];   // [N,3] fp32
    const float* tmpl = (const float*)d_in[1];   // [M,3] fp32
    float* out = (float*)d_out;                  // scalar fp32

    const int N = in_sizes[0] / 3;               // 50000
    const int M = in_sizes[1] / 3;               // 6890

    const int sChunks = (N + SC - 1) / SC;       // 170 for N=50000
    const int tChunks = (M + TPB - 1) / TPB;     // 3
    const int Mpad = tChunks * TPB;              // 6912

    float* pmin = (float*)d_ws;                  // [sChunks][Mpad] partial mins

    dim3 grid(sChunks, tChunks);
    pdl_main<<<grid, BLK, 0, stream>>>(scan, tmpl, pmin, out, M, N, Mpad);

    pdl_reduce<<<Mpad / BLK, BLK, 0, stream>>>(pmin, out, M, Mpad, sChunks);
}

// Round 3
// 87.068 us; speedup vs baseline: 1.9273x; 1.4394x over previous
//
#include <hip/hip_runtime.h>
#include <hip/hip_bf16.h>

#define TM 9            // template points per thread (register-tiled)
#define BLK 256         // threads per block
#define TPB (BLK * TM)  // 2304 templates per template-chunk -> 3 chunks = 6912
#define SCPAD 152       // scan points per chunk (LDS tile), multiple of 8
#define THRESH 0.1f
#define KEY_MAX 0xFFFFFFFFu

// Order-preserving float->uint map (valid for all finite floats incl. tiny
// negatives from rounding): min in key space == min in float space.
__device__ __forceinline__ unsigned int f2key(float f) {
    unsigned int b = __float_as_uint(f);
    return (b & 0x80000000u) ? ~b : (b | 0x80000000u);
}
__device__ __forceinline__ float key2f(unsigned int k) {
    return __uint_as_float((k & 0x80000000u) ? (k & 0x7FFFFFFFu) : ~k);
}

// Init: sentinel the global min array, zero the output scalar.
__global__ __launch_bounds__(BLK) void pdl_init(unsigned int* __restrict__ gmin,
                                                float* __restrict__ out, int Mpad) {
    const int i = blockIdx.x * BLK + threadIdx.x;
    if (i < Mpad) gmin[i] = KEY_MAX;
    if (i == 0) out[0] = 0.0f;
}

// Each block: one (scan-chunk, template-chunk) tile. Template tile in
// registers; scan chunk packed {-2x,-2y,-2z,|s|^2} in LDS (broadcast reads).
// Inner math: e = |s|^2 - 2 s.t (3 FMA/pair) + min-tree folding to v_min3
// (0.5 op/pair) -> 3.5 VALU ops per pair. Block min -> atomicMin(gmin).
__global__ __launch_bounds__(BLK) void pdl_main(const float* __restrict__ scan,
                                                const float* __restrict__ tmpl,
                                                unsigned int* __restrict__ gmin,
                                                int M, int N) {
    __shared__ float4 sp[SCPAD];
    const int tid = threadIdx.x;

    // Stage + pack this block's scan chunk.
    const int j0 = blockIdx.x * SCPAD;
    for (int p = tid; p < SCPAD; p += BLK) {
        const int j = j0 + p;
        float4 q = make_float4(0.0f, 0.0f, 0.0f, 3e30f);  // sentinel: huge dist
        if (j < N) {
            const float x = scan[3 * j + 0];
            const float y = scan[3 * j + 1];
            const float z = scan[3 * j + 2];
            q = make_float4(-2.0f * x, -2.0f * y, -2.0f * z, x * x + y * y + z * z);
        }
        sp[p] = q;
    }

    // Register-resident template tile.
    const int m0 = blockIdx.y * TPB + tid;
    float tx[TM], ty[TM], tz[TM], t2[TM], mn[TM];
#pragma unroll
    for (int k = 0; k < TM; ++k) {
        int m = m0 + k * BLK;
        if (m >= M) m = M - 1;  // clamped duplicate; store masked below
        const float x = tmpl[3 * m + 0];
        const float y = tmpl[3 * m + 1];
        const float z = tmpl[3 * m + 2];
        tx[k] = x; ty[k] = y; tz[k] = z;
        t2[k] = x * x + y * y + z * z;
        mn[k] = 3e30f;
    }

    __syncthreads();

#pragma unroll 2
    for (int jj = 0; jj < SCPAD; jj += 4) {
        const float4 s0 = sp[jj + 0];
        const float4 s1 = sp[jj + 1];
        const float4 s2 = sp[jj + 2];
        const float4 s3 = sp[jj + 3];
#pragma unroll
        for (int k = 0; k < TM; ++k) {
            const float e0 = fmaf(s0.x, tx[k], fmaf(s0.y, ty[k], fmaf(s0.z, tz[k], s0.w)));
            const float e1 = fmaf(s1.x, tx[k], fmaf(s1.y, ty[k], fmaf(s1.z, tz[k], s1.w)));
            const float e2 = fmaf(s2.x, tx[k], fmaf(s2.y, ty[k], fmaf(s2.z, tz[k], s2.w)));
            const float e3 = fmaf(s3.x, tx[k], fmaf(s3.y, ty[k], fmaf(s3.z, tz[k], s3.w)));
            // fold to 2x v_min3_f32: min3(e0,e1,e2); min3(x,e3,mn)
            const float x = fminf(fminf(e0, e1), e2);
            mn[k] = fminf(fminf(x, e3), mn[k]);
        }
    }

#pragma unroll
    for (int k = 0; k < TM; ++k) {
        const int m = m0 + k * BLK;
        if (m < M) atomicMin(&gmin[m], f2key(mn[k] + t2[k]));
    }
}

// Unmap, threshold, block-reduce, atomicAdd. 27 blocks, trivial.
__global__ __launch_bounds__(BLK) void pdl_final(const unsigned int* __restrict__ gmin,
                                                 float* __restrict__ out, int M) {
    const int m = blockIdx.x * BLK + threadIdx.x;
    float s = 0.0f;
    if (m < M) {
        const float v = key2f(gmin[m]);
        if (v < THRESH) s = v;
    }

#pragma unroll
    for (int off = 32; off > 0; off >>= 1) s += __shfl_down(s, off, 64);

    __shared__ float ls[BLK / 64];
    const int lane = threadIdx.x & 63;
    const int w = threadIdx.x >> 6;
    if (lane == 0) ls[w] = s;
    __syncthreads();
    if (threadIdx.x == 0) {
        float t = 0.0f;
#pragma unroll
        for (int i = 0; i < BLK / 64; ++i) t += ls[i];
        atomicAdd(out, t);
    }
}

extern "C" void kernel_launch(void* const* d_in, const int* in_sizes, int n_in,
                              void* d_out, int out_size, void* d_ws, size_t ws_size,
                              hipStream_t stream) {
    const float* scan = (const float*)d_in[0];   // [N,3] fp32
    const float* tmpl = (const float*)d_in[1];   // [M,3] fp32
    float* out = (float*)d_out;                  // scalar fp32

    const int N = in_sizes[0] / 3;               // 50000
    const int M = in_sizes[1] / 3;               // 6890

    const int sChunks = (N + SCPAD - 1) / SCPAD; // 329 -> grid 987 blocks (~4/CU)
    const int tChunks = (M + TPB - 1) / TPB;     // 3
    const int Mpad = tChunks * TPB;              // 6912

    unsigned int* gmin = (unsigned int*)d_ws;    // [Mpad] global min keys

    pdl_init<<<(Mpad + BLK - 1) / BLK, BLK, 0, stream>>>(gmin, out, Mpad);

    dim3 grid(sChunks, tChunks);
    pdl_main<<<grid, BLK, 0, stream>>>(scan, tmpl, gmin, M, N);

    pdl_final<<<(M + BLK - 1) / BLK, BLK, 0, stream>>>(gmin, out, M);
}

// Round 4
// 86.597 us; speedup vs baseline: 1.9378x; 1.0054x over previous
//
#include <hip/hip_runtime.h>
#include <hip/hip_bf16.h>

#define TM 9            // template points per thread (register-tiled)
#define BLK 256         // threads per block
#define TPB (BLK * TM)  // 2304 templates per template-chunk -> 3 chunks = 6912
#define SCPAD 152       // scan points per chunk (multiple of 8: 4 pts/iter x unroll 2)
#define NPAIR (SCPAD / 2)
#define THRESH 0.1f
#define KEY_MAX 0xFFFFFFFFu

typedef float v2f __attribute__((ext_vector_type(2)));

__device__ __forceinline__ v2f splat2(float x) { v2f r; r.x = x; r.y = x; return r; }
__device__ __forceinline__ v2f mk2(float a, float b) { v2f r; r.x = a; r.y = b; return r; }
// <2 x float> fma -> v_pk_fma_f32 on gfx90a+ (packed FP32 pipe)
__device__ __forceinline__ v2f pkfma(v2f a, v2f b, v2f c) {
    return __builtin_elementwise_fma(a, b, c);
}
__device__ __forceinline__ float min3f(float a, float b, float c) {
    return fminf(fminf(a, b), c);  // -> v_min3_f32
}

// Order-preserving float->uint map: min in key space == min in float space.
__device__ __forceinline__ unsigned int f2key(float f) {
    unsigned int b = __float_as_uint(f);
    return (b & 0x80000000u) ? ~b : (b | 0x80000000u);
}
__device__ __forceinline__ float key2f(unsigned int k) {
    return __uint_as_float((k & 0x80000000u) ? (k & 0x7FFFFFFFu) : ~k);
}

// Init: sentinel the global min array, zero the output scalar.
__global__ __launch_bounds__(BLK) void pdl_init(unsigned int* __restrict__ gmin,
                                                float* __restrict__ out, int Mpad) {
    const int i = blockIdx.x * BLK + threadIdx.x;
    if (i < Mpad) gmin[i] = KEY_MAX;
    if (i == 0) out[0] = 0.0f;
}

// Each block: one (scan-chunk, template-chunk) tile. Template tile in
// registers; scan chunk in LDS, PRE-PAIRED for packed FP32:
//   spA[p] = {-2x0, -2x1, -2y0, -2y1}   spB[p] = {-2z0, -2z1, w0, w1}
// so each ds_read_b128 yields aligned VGPR pairs feeding v_pk_fma_f32.
// Inner math per 4 scan points per template: 6 pk-fma + 2 min3 = 2.0 inst/pair.
__global__ __launch_bounds__(BLK) void pdl_main(const float* __restrict__ scan,
                                                const float* __restrict__ tmpl,
                                                unsigned int* __restrict__ gmin,
                                                int M, int N) {
    __shared__ float4 spA[NPAIR];
    __shared__ float4 spB[NPAIR];
    const int tid = threadIdx.x;

    // Stage + pack this block's scan chunk (pair layout).
    const int j0 = blockIdx.x * SCPAD;
    for (int p = tid; p < NPAIR; p += BLK) {
        const int j = j0 + 2 * p;
        float x0 = 0.f, y0 = 0.f, z0 = 0.f, w0 = 3e30f;  // sentinel: huge dist
        float x1 = 0.f, y1 = 0.f, z1 = 0.f, w1 = 3e30f;
        if (j < N) {
            x0 = scan[3 * j + 0]; y0 = scan[3 * j + 1]; z0 = scan[3 * j + 2];
            w0 = x0 * x0 + y0 * y0 + z0 * z0;
        }
        if (j + 1 < N) {
            x1 = scan[3 * j + 3]; y1 = scan[3 * j + 4]; z1 = scan[3 * j + 5];
            w1 = x1 * x1 + y1 * y1 + z1 * z1;
        }
        spA[p] = make_float4(-2.f * x0, -2.f * x1, -2.f * y0, -2.f * y1);
        spB[p] = make_float4(-2.f * z0, -2.f * z1, w0, w1);
    }

    // Register-resident template tile.
    const int m0 = blockIdx.y * TPB + tid;
    float tx[TM], ty[TM], tz[TM], t2[TM], mn[TM];
#pragma unroll
    for (int k = 0; k < TM; ++k) {
        int m = m0 + k * BLK;
        if (m >= M) m = M - 1;  // clamped duplicate; store masked below
        const float x = tmpl[3 * m + 0];
        const float y = tmpl[3 * m + 1];
        const float z = tmpl[3 * m + 2];
        tx[k] = x; ty[k] = y; tz[k] = z;
        t2[k] = x * x + y * y + z * z;
        mn[k] = 3e30f;
    }

    __syncthreads();

#pragma unroll 2
    for (int pp = 0; pp < NPAIR; pp += 2) {
        const float4 a0 = spA[pp + 0], b0 = spB[pp + 0];
        const float4 a1 = spA[pp + 1], b1 = spB[pp + 1];
#pragma unroll
        for (int k = 0; k < TM; ++k) {
            // e = w - 2 s.t for two scan points at once (3 pk-fma each)
            const v2f e0 = pkfma(mk2(a0.x, a0.y), splat2(tx[k]),
                           pkfma(mk2(a0.z, a0.w), splat2(ty[k]),
                           pkfma(mk2(b0.x, b0.y), splat2(tz[k]), mk2(b0.z, b0.w))));
            const v2f e1 = pkfma(mk2(a1.x, a1.y), splat2(tx[k]),
                           pkfma(mk2(a1.z, a1.w), splat2(ty[k]),
                           pkfma(mk2(b1.x, b1.y), splat2(tz[k]), mk2(b1.z, b1.w))));
            mn[k] = min3f(min3f(e0.x, e0.y, e1.x), e1.y, mn[k]);  // 2x v_min3
        }
    }

#pragma unroll
    for (int k = 0; k < TM; ++k) {
        const int m = m0 + k * BLK;
        if (m < M) atomicMin(&gmin[m], f2key(mn[k] + t2[k]));
    }
}

// Unmap, threshold, block-reduce, atomicAdd. 27 blocks, trivial.
__global__ __launch_bounds__(BLK) void pdl_final(const unsigned int* __restrict__ gmin,
                                                 float* __restrict__ out, int M) {
    const int m = blockIdx.x * BLK + threadIdx.x;
    float s = 0.0f;
    if (m < M) {
        const float v = key2f(gmin[m]);
        if (v < THRESH) s = v;
    }

#pragma unroll
    for (int off = 32; off > 0; off >>= 1) s += __shfl_down(s, off, 64);

    __shared__ float ls[BLK / 64];
    const int lane = threadIdx.x & 63;
    const int w = threadIdx.x >> 6;
    if (lane == 0) ls[w] = s;
    __syncthreads();
    if (threadIdx.x == 0) {
        float t = 0.0f;
#pragma unroll
        for (int i = 0; i < BLK / 64; ++i) t += ls[i];
        atomicAdd(out, t);
    }
}

extern "C" void kernel_launch(void* const* d_in, const int* in_sizes, int n_in,
                              void* d_out, int out_size, void* d_ws, size_t ws_size,
                              hipStream_t stream) {
    const float* scan = (const float*)d_in[0];   // [N,3] fp32
    const float* tmpl = (const float*)d_in[1];   // [M,3] fp32
    float* out = (float*)d_out;                  // scalar fp32

    const int N = in_sizes[0] / 3;               // 50000
    const int M = in_sizes[1] / 3;               // 6890

    const int sChunks = (N + SCPAD - 1) / SCPAD; // 329 -> grid 987 blocks (~4/CU)
    const int tChunks = (M + TPB - 1) / TPB;     // 3
    const int Mpad = tChunks * TPB;              // 6912

    unsigned int* gmin = (unsigned int*)d_ws;    // [Mpad] global min keys

    pdl_init<<<(Mpad + BLK - 1) / BLK, BLK, 0, stream>>>(gmin, out, Mpad);

    dim3 grid(sChunks, tChunks);
    pdl_main<<<grid, BLK, 0, stream>>>(scan, tmpl, gmin, M, N);

    pdl_final<<<(M + BLK - 1) / BLK, BLK, 0, stream>>>(gmin, out, M);
}

// Round 5
// 86.264 us; speedup vs baseline: 1.9453x; 1.0039x over previous
//
#include <hip/hip_runtime.h>
#include <hip/hip_bf16.h>

#define TM 9            // template points per thread (register-tiled, named scalars)
#define BLK 256         // threads per block
#define TPB (BLK * TM)  // 2304 templates per template-chunk -> 3 chunks = 6912
#define SCPAD 152       // scan points per chunk (multiple of 8)
#define THRESH 0.1f
#define KEY_MAX 0xFFFFFFFFu

// Order-preserving float->uint map: min in key space == min in float space.
__device__ __forceinline__ unsigned int f2key(float f) {
    unsigned int b = __float_as_uint(f);
    return (b & 0x80000000u) ? ~b : (b | 0x80000000u);
}
__device__ __forceinline__ float key2f(unsigned int k) {
    return __uint_as_float((k & 0x80000000u) ? (k & 0x7FFFFFFFu) : ~k);
}

// Init: sentinel the global min array, zero the output scalar.
__global__ __launch_bounds__(BLK) void pdl_init(unsigned int* __restrict__ gmin,
                                                float* __restrict__ out, int Mpad) {
    const int i = blockIdx.x * BLK + threadIdx.x;
    if (i < Mpad) gmin[i] = KEY_MAX;
    if (i == 0) out[0] = 0.0f;
}

// Macro-unrolled over the 9 template points: NO private arrays anywhere, so the
// tile cannot be demoted to scratch or rematerialized (R1 showed VGPR_Count=28,
// i.e. the 45-float tile was never register-resident -> per-iter reloads).
#define FOR_K(OP) OP(0) OP(1) OP(2) OP(3) OP(4) OP(5) OP(6) OP(7) OP(8)

__global__ __launch_bounds__(BLK) void pdl_main(const float* __restrict__ scan,
                                                const float* __restrict__ tmpl,
                                                unsigned int* __restrict__ gmin,
                                                int M, int N) {
    __shared__ float4 sp[SCPAD];
    const int tid = threadIdx.x;

    // Stage + pack this block's scan chunk: {-2x, -2y, -2z, |s|^2}.
    const int j0 = blockIdx.x * SCPAD;
    for (int p = tid; p < SCPAD; p += BLK) {
        const int j = j0 + p;
        float4 q = make_float4(0.0f, 0.0f, 0.0f, 3e30f);  // sentinel: huge dist
        if (j < N) {
            const float x = scan[3 * j + 0];
            const float y = scan[3 * j + 1];
            const float z = scan[3 * j + 2];
            q = make_float4(-2.0f * x, -2.0f * y, -2.0f * z, x * x + y * y + z * z);
        }
        sp[p] = q;
    }

    const int m0 = blockIdx.y * TPB + tid;

#define DECL_T(i) float tx##i, ty##i, tz##i, tq##i, mn##i;
    FOR_K(DECL_T)

#define LOAD_T(i) {                                                     \
        int m = m0 + (i) * BLK;                                         \
        if (m >= M) m = M - 1; /* clamped dup; store masked below */    \
        const float x = tmpl[3 * m + 0];                                \
        const float y = tmpl[3 * m + 1];                                \
        const float z = tmpl[3 * m + 2];                                \
        tx##i = x; ty##i = y; tz##i = z;                                \
        tq##i = x * x + y * y + z * z;                                  \
        mn##i = 3e30f;                                                  \
    }
    FOR_K(LOAD_T)

    // Pin the tile in VGPRs: opaque touch makes rematerialization illegal.
#define PIN_T(i) asm volatile("" : "+v"(tx##i), "+v"(ty##i), "+v"(tz##i), "+v"(tq##i));
    FOR_K(PIN_T)

    __syncthreads();

#pragma unroll 2
    for (int jj = 0; jj < SCPAD; jj += 4) {
        const float4 s0 = sp[jj + 0];
        const float4 s1 = sp[jj + 1];
        const float4 s2 = sp[jj + 2];
        const float4 s3 = sp[jj + 3];
        // e = |s|^2 - 2 s.t (3 fma), fold mins into 2x v_min3: 3.5 op/pair.
#define STEP_T(i) {                                                                   \
        const float e0 = fmaf(s0.x, tx##i, fmaf(s0.y, ty##i, fmaf(s0.z, tz##i, s0.w))); \
        const float e1 = fmaf(s1.x, tx##i, fmaf(s1.y, ty##i, fmaf(s1.z, tz##i, s1.w))); \
        const float e2 = fmaf(s2.x, tx##i, fmaf(s2.y, ty##i, fmaf(s2.z, tz##i, s2.w))); \
        const float e3 = fmaf(s3.x, tx##i, fmaf(s3.y, ty##i, fmaf(s3.z, tz##i, s3.w))); \
        const float u  = fminf(fminf(e0, e1), e2);                                    \
        mn##i = fminf(fminf(u, e3), mn##i);                                           \
    }
        FOR_K(STEP_T)
    }

#define STORE_T(i) {                                                    \
        const int m = m0 + (i) * BLK;                                   \
        if (m < M) atomicMin(&gmin[m], f2key(mn##i + tq##i));           \
    }
    FOR_K(STORE_T)
}

// Unmap, threshold, block-reduce, atomicAdd. 27 blocks, trivial.
__global__ __launch_bounds__(BLK) void pdl_final(const unsigned int* __restrict__ gmin,
                                                 float* __restrict__ out, int M) {
    const int m = blockIdx.x * BLK + threadIdx.x;
    float s = 0.0f;
    if (m < M) {
        const float v = key2f(gmin[m]);
        if (v < THRESH) s = v;
    }

#pragma unroll
    for (int off = 32; off > 0; off >>= 1) s += __shfl_down(s, off, 64);

    __shared__ float ls[BLK / 64];
    const int lane = threadIdx.x & 63;
    const int w = threadIdx.x >> 6;
    if (lane == 0) ls[w] = s;
    __syncthreads();
    if (threadIdx.x == 0) {
        float t = 0.0f;
#pragma unroll
        for (int i = 0; i < BLK / 64; ++i) t += ls[i];
        atomicAdd(out, t);
    }
}

extern "C" void kernel_launch(void* const* d_in, const int* in_sizes, int n_in,
                              void* d_out, int out_size, void* d_ws, size_t ws_size,
                              hipStream_t stream) {
    const float* scan = (const float*)d_in[0];   // [N,3] fp32
    const float* tmpl = (const float*)d_in[1];   // [M,3] fp32
    float* out = (float*)d_out;                  // scalar fp32

    const int N = in_sizes[0] / 3;               // 50000
    const int M = in_sizes[1] / 3;               // 6890

    const int sChunks = (N + SCPAD - 1) / SCPAD; // 329
    const int tChunks = (M + TPB - 1) / TPB;     // 3
    const int Mpad = tChunks * TPB;              // 6912

    unsigned int* gmin = (unsigned int*)d_ws;    // [Mpad] global min keys

    pdl_init<<<(Mpad + BLK - 1) / BLK, BLK, 0, stream>>>(gmin, out, Mpad);

    dim3 grid(sChunks, tChunks);
    pdl_main<<<grid, BLK, 0, stream>>>(scan, tmpl, gmin, M, N);

    pdl_final<<<(M + BLK - 1) / BLK, BLK, 0, stream>>>(gmin, out, M);
}